// Round 7
// baseline (956.274 us; speedup 1.0000x reference)
//
#include <hip/hip_runtime.h>
#include <hip/hip_bf16.h>

typedef short bf16x8 __attribute__((ext_vector_type(8)));
typedef float f32x4  __attribute__((ext_vector_type(4)));
typedef unsigned short u16x4 __attribute__((ext_vector_type(4)));

#define NB    32
#define NH    128
#define DV    512
#define DQK   576
#define NKV   8192
#define NTOP  2048
#define LSTR  40     // fallback-path LDS stride (32 data + 8 pad)
#define LSTR2 72     // GEMM LDS row stride in bf16 (64 data + 8 pad) = 144B, 16B-aligned
#define LSTRT 132    // transpose tile stride (128 + 4) u16
#define SCALE 0.041666666666666664f   // 1/sqrt(576)

__device__ __forceinline__ unsigned bfbits(float x) {
  union { float f; unsigned u; } c; c.f = x;
  return (c.u + 0x7FFFu + ((c.u >> 16) & 1u)) >> 16;   // RNE; inputs never NaN
}
__device__ __forceinline__ unsigned pk2(float x, float y) {
  return bfbits(x) | (bfbits(y) << 16);
}
__device__ __forceinline__ short f2bf(float x) { return (short)bfbits(x); }
__device__ __forceinline__ u16x4 cvt4(float4 v) {
  u16x4 o;
  o.x = (unsigned short)bfbits(v.x); o.y = (unsigned short)bfbits(v.y);
  o.z = (unsigned short)bfbits(v.z); o.w = (unsigned short)bfbits(v.w);
  return o;
}

// ================================ FAST PATH (needs ~181 MB ws) ================================

// ---------------- Kernel 0: gather selected KV rows, convert fp32->bf16 once.
// Writes Kb[b][k][576] (k-major, for QK's B) and Vt[b][d][k] (d-major, for PV's B), plus Qb.
__global__ __launch_bounds__(256) void gather_cvt(const float* __restrict__ Q, const float* __restrict__ KV,
                                                  const int* __restrict__ Idx,
                                                  unsigned short* __restrict__ Kb, unsigned short* __restrict__ Vt,
                                                  unsigned short* __restrict__ Qb) {
  __shared__ unsigned short Tl[128 * LSTRT];   // 33.8 KB
  int wg = blockIdx.x;
  int t = threadIdx.x;

  if (wg >= NB * 16) {                          // ---- Q conversion: one block per batch
    int b = wg - NB * 16;
    int r0 = t >> 5, lane32 = t & 31;
    for (int pass = 0; pass < 16; ++pass) {
      int r = pass * 8 + r0;
      const float4* src = (const float4*)(Q + ((size_t)b * NH + r) * DQK);
      unsigned short* dst = Qb + ((size_t)b * NH + r) * DQK;
#pragma unroll
      for (int c = 0; c < 5; ++c) {
        int i4 = c * 32 + lane32;
        if (i4 < 144) *(u16x4*)(dst + i4 * 4) = cvt4(src[i4]);
      }
    }
    return;
  }

  int b = wg >> 4, kt = wg & 15;                // 16 key-tiles of 128 rows

  // d-chunks 0..3 (128 dims each): Kb write + LDS stash + transposed Vt write
  for (int c = 0; c < 4; ++c) {
    {
      int r02 = t >> 5, lane32 = t & 31;
      for (int pass = 0; pass < 16; ++pass) {   // half-wave per row, 8 rows/pass
        int r = pass * 8 + r02;
        int n = kt * 128 + r;
        int idx = Idx[b * NTOP + n];
        float4 v = ((const float4*)(KV + ((size_t)b * NKV + (size_t)idx) * DQK + c * 128))[lane32];
        u16x4 o = cvt4(v);
        *(u16x4*)(Kb + ((size_t)b * NTOP + n) * DQK + c * 128 + lane32 * 4) = o;
        *(u16x4*)(&Tl[r * LSTRT + lane32 * 4]) = o;
      }
    }
    __syncthreads();
    // transposed out: Vt[b][c*128+dl][kt*128 + k]; 2 threads per d-row, 128B contiguous each
    {
      int dl = t >> 1, hk = t & 1;
      unsigned short* vo = Vt + ((size_t)b * DV + (size_t)(c * 128 + dl)) * NTOP + kt * 128 + hk * 64;
#pragma unroll
      for (int g = 0; g < 8; ++g) {
        int k0 = hk * 64 + g * 8;
        uint4 w;
        w.x = (unsigned)Tl[(k0 + 0) * LSTRT + dl] | ((unsigned)Tl[(k0 + 1) * LSTRT + dl] << 16);
        w.y = (unsigned)Tl[(k0 + 2) * LSTRT + dl] | ((unsigned)Tl[(k0 + 3) * LSTRT + dl] << 16);
        w.z = (unsigned)Tl[(k0 + 4) * LSTRT + dl] | ((unsigned)Tl[(k0 + 5) * LSTRT + dl] << 16);
        w.w = (unsigned)Tl[(k0 + 6) * LSTRT + dl] | ((unsigned)Tl[(k0 + 7) * LSTRT + dl] << 16);
        *(uint4*)(vo + g * 8) = w;
      }
    }
    __syncthreads();
  }

  // tail dims [512,576): Kb only (quarter-wave per row)
  {
    int r0q = t >> 4, lane16 = t & 15;
    for (int pass = 0; pass < 8; ++pass) {
      int r = pass * 16 + r0q;
      int n = kt * 128 + r;
      int idx = Idx[b * NTOP + n];
      float4 v = ((const float4*)(KV + ((size_t)b * NKV + (size_t)idx) * DQK + 512))[lane16];
      *(u16x4*)(Kb + ((size_t)b * NTOP + n) * DQK + 512 + lane16 * 4) = cvt4(v);
    }
  }
}

// ---------------- Kernel 1: S = scale * Qb . Kb^T  (128h x 128k tile, K=576, BK=64, reg-prefetch) ----------------
__global__ __launch_bounds__(256) void gemm_qk(const unsigned short* __restrict__ Qb, const unsigned short* __restrict__ Kb,
                                               float* __restrict__ S) {
  __shared__ unsigned short As[128 * LSTR2];
  __shared__ unsigned short Bs[128 * LSTR2];
  int wg = blockIdx.x;
  int b = wg >> 4, nt = wg & 15;
  int t = threadIdx.x;
  int row = t >> 1, half = t & 1;               // 2 threads/row, 32 bf16 (64B) each per BK-tile

  const uint4* ag = (const uint4*)(Qb + ((size_t)b * NH + row) * DQK) + half * 4;
  const uint4* bg = (const uint4*)(Kb + ((size_t)b * NTOP + nt * 128 + row) * DQK) + half * 4;
  unsigned short* aw = &As[row * LSTR2 + half * 32];
  unsigned short* bw = &Bs[row * LSTR2 + half * 32];

  int lane = t & 63, wv = t >> 6;
  int wm = wv & 1, wn = wv >> 1;                // 2x2 waves, 64x64 each
  int m16 = lane & 15, quad = lane >> 4;

  f32x4 acc[4][4] = {};
  uint4 ra[4], rb[4];
#pragma unroll
  for (int u = 0; u < 4; ++u) { ra[u] = ag[u]; rb[u] = bg[u]; }

  for (int kk = 0; kk < 9; ++kk) {              // 576 / 64
#pragma unroll
    for (int u = 0; u < 4; ++u) {
      *(uint4*)(aw + u * 8) = ra[u];
      *(uint4*)(bw + u * 8) = rb[u];
    }
    __syncthreads();
    int kn = (kk < 8) ? kk + 1 : kk;            // prefetch next tile into regs; latency hides under MFMA
    uint4 na[4], nb[4];
#pragma unroll
    for (int u = 0; u < 4; ++u) { na[u] = ag[kn * 8 + u]; nb[u] = bg[kn * 8 + u]; }
#pragma unroll
    for (int ks = 0; ks < 2; ++ks) {
      bf16x8 af[4], bfr[4];
#pragma unroll
      for (int i = 0; i < 4; ++i) af[i]  = *(const bf16x8*)&As[(wm * 64 + i * 16 + m16) * LSTR2 + ks * 32 + quad * 8];
#pragma unroll
      for (int j = 0; j < 4; ++j) bfr[j] = *(const bf16x8*)&Bs[(wn * 64 + j * 16 + m16) * LSTR2 + ks * 32 + quad * 8];
#pragma unroll
      for (int i = 0; i < 4; ++i)
#pragma unroll
        for (int j = 0; j < 4; ++j)
          acc[i][j] = __builtin_amdgcn_mfma_f32_16x16x32_bf16(af[i], bfr[j], acc[i][j], 0, 0, 0);
    }
    __syncthreads();
#pragma unroll
    for (int u = 0; u < 4; ++u) { ra[u] = na[u]; rb[u] = nb[u]; }
  }

  // C/D layout: col = lane&15 (key), row = quad*4 + reg (head)
#pragma unroll
  for (int i = 0; i < 4; ++i)
#pragma unroll
    for (int j = 0; j < 4; ++j)
#pragma unroll
      for (int r = 0; r < 4; ++r) {
        int h = wm * 64 + i * 16 + quad * 4 + r;
        int n = nt * 128 + wn * 64 + j * 16 + m16;
        S[((size_t)b * NH + h) * NTOP + n] = acc[i][j][r] * SCALE;
      }
}

// ---------------- Kernel 2: rowwise softmax over 2048, write normalized bf16 P (both paths) ----------------
__global__ __launch_bounds__(256) void softmax_k(const float* __restrict__ S, unsigned short* __restrict__ P) {
  int row = blockIdx.x;                    // b*128 + h
  const float* s = S + (size_t)row * NTOP;
  unsigned short* p = P + (size_t)row * NTOP;
  int t = threadIdx.x;
  int lane = t & 63, wv = t >> 6;
  __shared__ float red[4];

  float4 v0 = *(const float4*)(s + t * 4);
  float4 v1 = *(const float4*)(s + 1024 + t * 4);

  float lm = fmaxf(fmaxf(fmaxf(v0.x, v0.y), fmaxf(v0.z, v0.w)),
                   fmaxf(fmaxf(v1.x, v1.y), fmaxf(v1.z, v1.w)));
  for (int off = 32; off > 0; off >>= 1) lm = fmaxf(lm, __shfl_down(lm, off));
  if (lane == 0) red[wv] = lm;
  __syncthreads();
  float m = fmaxf(fmaxf(red[0], red[1]), fmaxf(red[2], red[3]));

  float e0 = expf(v0.x - m), e1 = expf(v0.y - m), e2 = expf(v0.z - m), e3 = expf(v0.w - m);
  float e4 = expf(v1.x - m), e5 = expf(v1.y - m), e6 = expf(v1.z - m), e7 = expf(v1.w - m);
  float ls = ((e0 + e1) + (e2 + e3)) + ((e4 + e5) + (e6 + e7));
  for (int off = 32; off > 0; off >>= 1) ls += __shfl_down(ls, off);
  __syncthreads();                          // all waves done reading red from max phase
  if (lane == 0) red[wv] = ls;
  __syncthreads();
  float inv = 1.0f / (((red[0] + red[1]) + (red[2] + red[3])));

  uint2 o0 = { pk2(e0 * inv, e1 * inv), pk2(e2 * inv, e3 * inv) };
  uint2 o1 = { pk2(e4 * inv, e5 * inv), pk2(e6 * inv, e7 * inv) };
  *(uint2*)(p + t * 4) = o0;
  *(uint2*)(p + 1024 + t * 4) = o1;
}

// ---------------- Kernel 3: Pt[ks][b][h][d] = P[b][h][k] . Vt[b][d][k]  (BK=64, K-split x4, plain stores) ----------------
// Block remap: the 4 d-tile blocks sharing one (b,ks) P-slice are congruent mod 8 -> same XCD -> P re-reads hit L2.
__global__ __launch_bounds__(256) void gemm_pv(const unsigned short* __restrict__ P, const unsigned short* __restrict__ Vt,
                                               float* __restrict__ Pt) {
  __shared__ unsigned short As[128 * LSTR2];
  __shared__ unsigned short Bs[128 * LSTR2];
  int wg = blockIdx.x;
  int nt = (wg >> 3) & 3;                              // d-tile: varies while wg%8 (XCD) stays fixed
  int combo = ((wg >> 5) << 3) | (wg & 7);             // 0..127 = b*4 + ks
  int b = combo >> 2, ks = combo & 3;
  int t = threadIdx.x;
  int row = t >> 1, half = t & 1;

  const uint4* ag = (const uint4*)(P  + ((size_t)b * NH + row) * NTOP + ks * 512) + half * 4;
  const uint4* bg = (const uint4*)(Vt + ((size_t)b * DV + nt * 128 + row) * NTOP + ks * 512) + half * 4;
  unsigned short* aw = &As[row * LSTR2 + half * 32];
  unsigned short* bw = &Bs[row * LSTR2 + half * 32];

  int lane = t & 63, wv = t >> 6;
  int wm = wv & 1, wn = wv >> 1;
  int m16 = lane & 15, quad = lane >> 4;

  f32x4 acc[4][4] = {};
  uint4 ra[4], rb[4];
#pragma unroll
  for (int u = 0; u < 4; ++u) { ra[u] = ag[u]; rb[u] = bg[u]; }

  for (int kk = 0; kk < 8; ++kk) {              // 512 / 64
#pragma unroll
    for (int u = 0; u < 4; ++u) {
      *(uint4*)(aw + u * 8) = ra[u];
      *(uint4*)(bw + u * 8) = rb[u];
    }
    __syncthreads();
    int kn = (kk < 7) ? kk + 1 : kk;
    uint4 na[4], nb[4];
#pragma unroll
    for (int u = 0; u < 4; ++u) { na[u] = ag[kn * 8 + u]; nb[u] = bg[kn * 8 + u]; }
#pragma unroll
    for (int ks2 = 0; ks2 < 2; ++ks2) {
      bf16x8 af[4], bfr[4];
#pragma unroll
      for (int i = 0; i < 4; ++i) af[i]  = *(const bf16x8*)&As[(wm * 64 + i * 16 + m16) * LSTR2 + ks2 * 32 + quad * 8];
#pragma unroll
      for (int j = 0; j < 4; ++j) bfr[j] = *(const bf16x8*)&Bs[(wn * 64 + j * 16 + m16) * LSTR2 + ks2 * 32 + quad * 8];
#pragma unroll
      for (int i = 0; i < 4; ++i)
#pragma unroll
        for (int j = 0; j < 4; ++j)
          acc[i][j] = __builtin_amdgcn_mfma_f32_16x16x32_bf16(af[i], bfr[j], acc[i][j], 0, 0, 0);
    }
    __syncthreads();
#pragma unroll
    for (int u = 0; u < 4; ++u) { ra[u] = na[u]; rb[u] = nb[u]; }
  }

  // plain coalesced stores to this K-split's partial buffer (no atomics, no d_out memset needed)
  float* po = Pt + (size_t)ks * ((size_t)NB * NH * DV);
#pragma unroll
  for (int i = 0; i < 4; ++i)
#pragma unroll
    for (int j = 0; j < 4; ++j)
#pragma unroll
      for (int r = 0; r < 4; ++r) {
        int h = wm * 64 + i * 16 + quad * 4 + r;
        int d = nt * 128 + wn * 64 + j * 16 + m16;
        po[((size_t)b * NH + h) * DV + d] = acc[i][j][r];
      }
}

// ---------------- Kernel 4: Out = sum of 4 K-split partials ----------------
__global__ __launch_bounds__(256) void reduce4(const float* __restrict__ Pt, float* __restrict__ Out) {
  const size_t N = (size_t)NB * NH * DV;
  size_t i = ((size_t)blockIdx.x * 256 + threadIdx.x) * 4;
  float4 a = *(const float4*)(Pt + i);
  float4 b = *(const float4*)(Pt + N + i);
  float4 c = *(const float4*)(Pt + 2 * N + i);
  float4 d = *(const float4*)(Pt + 3 * N + i);
  float4 o = { (a.x + b.x) + (c.x + d.x), (a.y + b.y) + (c.y + d.y),
               (a.z + b.z) + (c.z + d.z), (a.w + b.w) + (c.w + d.w) };
  *(float4*)(Out + i) = o;
}

// ================================ FALLBACK PATH (verified baseline, ~50 MB ws) ================================

__global__ __launch_bounds__(256) void gemm_qk_fb(const float* __restrict__ Q, const float* __restrict__ KV,
                                                  const int* __restrict__ Idx, float* __restrict__ S) {
  __shared__ short As[128 * LSTR];
  __shared__ short Bs[128 * LSTR];
  int wg = blockIdx.x;
  int b = wg >> 4, nt = wg & 15;
  int t = threadIdx.x;

  int row2 = t >> 1, half = t & 1;
  int idx = Idx[b * NTOP + nt * 128 + row2];
  const float* kvrow = KV + ((size_t)b * NKV + (size_t)idx) * DQK + half * 16;
  const float* qrow  = Q  + ((size_t)b * NH  + (size_t)row2) * DQK + half * 16;
  short* aw = &As[row2 * LSTR + half * 16];
  short* bw = &Bs[row2 * LSTR + half * 16];

  int lane = t & 63, wv = t >> 6;
  int wm = wv & 1, wn = wv >> 1;
  int m16 = lane & 15, quad = lane >> 4;

  f32x4 acc[4][4] = {};

  for (int kk = 0; kk < 18; ++kk) {
    __syncthreads();
    float4 q0 = *(const float4*)(qrow + 0);
    float4 q1 = *(const float4*)(qrow + 4);
    float4 q2 = *(const float4*)(qrow + 8);
    float4 q3 = *(const float4*)(qrow + 12);
    float4 k0 = *(const float4*)(kvrow + 0);
    float4 k1 = *(const float4*)(kvrow + 4);
    float4 k2 = *(const float4*)(kvrow + 8);
    float4 k3 = *(const float4*)(kvrow + 12);
    int4 wa0 = { (int)pk2(q0.x, q0.y), (int)pk2(q0.z, q0.w), (int)pk2(q1.x, q1.y), (int)pk2(q1.z, q1.w) };
    int4 wa1 = { (int)pk2(q2.x, q2.y), (int)pk2(q2.z, q2.w), (int)pk2(q3.x, q3.y), (int)pk2(q3.z, q3.w) };
    int4 wb0 = { (int)pk2(k0.x, k0.y), (int)pk2(k0.z, k0.w), (int)pk2(k1.x, k1.y), (int)pk2(k1.z, k1.w) };
    int4 wb1 = { (int)pk2(k2.x, k2.y), (int)pk2(k2.z, k2.w), (int)pk2(k3.x, k3.y), (int)pk2(k3.z, k3.w) };
    *(int4*)aw = wa0; *(int4*)(aw + 8) = wa1;
    *(int4*)bw = wb0; *(int4*)(bw + 8) = wb1;
    qrow += 32; kvrow += 32;
    __syncthreads();

    bf16x8 af[4], bfr[4];
#pragma unroll
    for (int i = 0; i < 4; ++i) af[i]  = *(const bf16x8*)&As[(wm * 64 + i * 16 + m16) * LSTR + quad * 8];
#pragma unroll
    for (int j = 0; j < 4; ++j) bfr[j] = *(const bf16x8*)&Bs[(wn * 64 + j * 16 + m16) * LSTR + quad * 8];
#pragma unroll
    for (int i = 0; i < 4; ++i)
#pragma unroll
      for (int j = 0; j < 4; ++j)
        acc[i][j] = __builtin_amdgcn_mfma_f32_16x16x32_bf16(af[i], bfr[j], acc[i][j], 0, 0, 0);
  }

#pragma unroll
  for (int i = 0; i < 4; ++i)
#pragma unroll
    for (int j = 0; j < 4; ++j)
#pragma unroll
      for (int r = 0; r < 4; ++r) {
        int h = wm * 64 + i * 16 + quad * 4 + r;
        int n = nt * 128 + wn * 64 + j * 16 + m16;
        S[((size_t)b * NH + h) * NTOP + n] = acc[i][j][r] * SCALE;
      }
}

__global__ __launch_bounds__(256) void gemm_pv_fb(const unsigned short* __restrict__ P, const float* __restrict__ KV,
                                                  const int* __restrict__ Idx, float* __restrict__ Out) {
  __shared__ short As[128 * LSTR];
  __shared__ short Bt[128 * LSTR];
  int wg = blockIdx.x;
  int b = wg >> 4, nt = (wg >> 2) & 3, ks = wg & 3;
  int t = threadIdx.x;

  int arow = t >> 1, ahalf = t & 1;
  const unsigned short* prow = P + ((size_t)b * NH + arow) * NTOP + ks * 512 + ahalf * 16;
  short* aw = &As[arow * LSTR + ahalf * 16];

  int brow = t & 31;
  int bcol = (t >> 5) * 16;
  const int* idxp = Idx + b * NTOP + ks * 512 + brow;
  short* bw = &Bt[bcol * LSTR + brow];

  int lane = t & 63, wv = t >> 6;
  int wm = wv & 1, wn = wv >> 1;
  int m16 = lane & 15, quad = lane >> 4;

  f32x4 acc[4][4] = {};

  for (int kk = 0; kk < 16; ++kk) {
    __syncthreads();
    uint4 p0 = *(const uint4*)(prow);
    uint4 p1 = *(const uint4*)(prow + 8);
    int idx = idxp[kk * 32];
    const float* vrow = KV + ((size_t)b * NKV + (size_t)idx) * DQK + nt * 128 + bcol;
    float4 v0 = *(const float4*)(vrow + 0);
    float4 v1 = *(const float4*)(vrow + 4);
    float4 v2 = *(const float4*)(vrow + 8);
    float4 v3 = *(const float4*)(vrow + 12);
    *(uint4*)aw = p0; *(uint4*)(aw + 8) = p1;
    prow += 32;
    bw[0 * LSTR]  = f2bf(v0.x); bw[1 * LSTR]  = f2bf(v0.y); bw[2 * LSTR]  = f2bf(v0.z); bw[3 * LSTR]  = f2bf(v0.w);
    bw[4 * LSTR]  = f2bf(v1.x); bw[5 * LSTR]  = f2bf(v1.y); bw[6 * LSTR]  = f2bf(v1.z); bw[7 * LSTR]  = f2bf(v1.w);
    bw[8 * LSTR]  = f2bf(v2.x); bw[9 * LSTR]  = f2bf(v2.y); bw[10 * LSTR] = f2bf(v2.z); bw[11 * LSTR] = f2bf(v2.w);
    bw[12 * LSTR] = f2bf(v3.x); bw[13 * LSTR] = f2bf(v3.y); bw[14 * LSTR] = f2bf(v3.z); bw[15 * LSTR] = f2bf(v3.w);
    __syncthreads();

    bf16x8 af[4], bfr[4];
#pragma unroll
    for (int i = 0; i < 4; ++i) af[i]  = *(const bf16x8*)&As[(wm * 64 + i * 16 + m16) * LSTR + quad * 8];
#pragma unroll
    for (int j = 0; j < 4; ++j) bfr[j] = *(const bf16x8*)&Bt[(wn * 64 + j * 16 + m16) * LSTR + quad * 8];
#pragma unroll
    for (int i = 0; i < 4; ++i)
#pragma unroll
      for (int j = 0; j < 4; ++j)
        acc[i][j] = __builtin_amdgcn_mfma_f32_16x16x32_bf16(af[i], bfr[j], acc[i][j], 0, 0, 0);
  }

#pragma unroll
  for (int i = 0; i < 4; ++i)
#pragma unroll
    for (int j = 0; j < 4; ++j)
#pragma unroll
      for (int r = 0; r < 4; ++r) {
        int h = wm * 64 + i * 16 + quad * 4 + r;
        int d = nt * 128 + wn * 64 + j * 16 + m16;
        atomicAdd(&Out[((size_t)b * NH + h) * DV + d], acc[i][j][r]);
      }
}

extern "C" void kernel_launch(void* const* d_in, const int* in_sizes, int n_in,
                              void* d_out, int out_size, void* d_ws, size_t ws_size,
                              hipStream_t stream) {
  (void)in_sizes; (void)n_in;
  const float* Q  = (const float*)d_in[0];
  const float* KV = (const float*)d_in[1];
  const int*  Idx = (const int*)d_in[2];
  float* Out = (float*)d_out;

  size_t szS  = (size_t)NB * NH * NTOP * 4;    // 33.55 MB
  size_t szKb = (size_t)NB * NTOP * DQK * 2;   // 75.50 MB
  size_t szVt = (size_t)NB * DV * NTOP * 2;    // 67.11 MB
  size_t szQb = (size_t)NB * NH * DQK * 2;     // 4.72 MB

  if (ws_size >= szS + szKb + szVt + szQb) {
    // -------- fast path (no atomics, no d_out memset) --------
    char* w = (char*)d_ws;
    float* S = (float*)w;                     w += szS;
    unsigned short* Kb = (unsigned short*)w;  w += szKb;
    unsigned short* Vt = (unsigned short*)w;  w += szVt;
    unsigned short* Qb = (unsigned short*)w;
    unsigned short* P = Kb;   // alias: Kb dead after gemm_qk
    float* Pt = S;            // alias: S dead after softmax; 4*NB*NH*DV*4 B == szS exactly

    gather_cvt<<<dim3(NB * 16 + NB), dim3(256), 0, stream>>>(Q, KV, Idx, Kb, Vt, Qb);
    gemm_qk<<<dim3(NB * 16), dim3(256), 0, stream>>>(Qb, Kb, S);
    softmax_k<<<dim3(NB * NH), dim3(256), 0, stream>>>(S, P);
    gemm_pv<<<dim3(NB * 16), dim3(256), 0, stream>>>(P, Vt, Pt);
    reduce4<<<dim3((NB * NH * DV) / 1024), dim3(256), 0, stream>>>(Pt, Out);
  } else {
    // -------- fallback: harness-verified baseline path --------
    float* S = (float*)d_ws;
    unsigned short* P = (unsigned short*)((char*)d_ws + szS);

    (void)hipMemsetAsync(d_out, 0, (size_t)out_size * sizeof(float), stream);
    gemm_qk_fb<<<dim3(NB * 16), dim3(256), 0, stream>>>(Q, KV, Idx, S);
    softmax_k<<<dim3(NB * NH), dim3(256), 0, stream>>>(S, P);
    gemm_pv_fb<<<dim3(NB * 16), dim3(256), 0, stream>>>(P, KV, Idx, Out);
  }
}

// Round 8
// 740.728 us; speedup vs baseline: 1.2910x; 1.2910x over previous
//
#include <hip/hip_runtime.h>
#include <hip/hip_bf16.h>

typedef short bf16x8 __attribute__((ext_vector_type(8)));
typedef float f32x4  __attribute__((ext_vector_type(4)));

#define NB    32
#define NH    128
#define DV    512
#define DQK   576
#define NKV   8192
#define NTOP  2048
#define LSTR  40          // LDS row stride in bf16 elems (32 data + 8 pad)
#define SCALE 0.041666666666666664f   // 1/sqrt(576)

__device__ __forceinline__ unsigned bfbits(float x) {
  union { float f; unsigned u; } c; c.f = x;
  return (c.u + 0x7FFFu + ((c.u >> 16) & 1u)) >> 16;   // RNE; inputs never NaN
}
__device__ __forceinline__ unsigned pk2(float x, float y) {
  return bfbits(x) | (bfbits(y) << 16);
}
__device__ __forceinline__ short f2bf(float x) { return (short)bfbits(x); }

// ---------------- Kernel 1: S[b][h][k] = scale * Q[b][h][:] . KV[b][idx[k]][:]  (K=576) ----------------
// Baseline structure + register prefetch: iteration kk+1's Q/KV chunks load into regs while MFMA runs on kk.
__global__ __launch_bounds__(256) void gemm_qk(const float* __restrict__ Q, const float* __restrict__ KV,
                                               const int* __restrict__ Idx, float* __restrict__ S) {
  __shared__ short As[128 * LSTR];
  __shared__ short Bs[128 * LSTR];
  int wg = blockIdx.x;
  int b = wg >> 4, nt = wg & 15;          // 16 key-tiles of 128
  int t = threadIdx.x;

  // staging assignment: 2 threads per row, 16 floats each per K-step
  int row2 = t >> 1, half = t & 1;
  int idx = Idx[b * NTOP + nt * 128 + row2];
  const float* kvrow = KV + ((size_t)b * NKV + (size_t)idx) * DQK + half * 16;
  const float* qrow  = Q  + ((size_t)b * NH  + (size_t)row2) * DQK + half * 16;
  short* aw = &As[row2 * LSTR + half * 16];
  short* bw = &Bs[row2 * LSTR + half * 16];

  int lane = t & 63, wv = t >> 6;
  int wm = wv & 1, wn = wv >> 1;          // 2x2 waves, 64x64 each
  int m16 = lane & 15, quad = lane >> 4;

  f32x4 acc[4][4] = {};

  // preload iteration 0
  float4 q0 = *(const float4*)(qrow + 0);
  float4 q1 = *(const float4*)(qrow + 4);
  float4 q2 = *(const float4*)(qrow + 8);
  float4 q3 = *(const float4*)(qrow + 12);
  float4 k0 = *(const float4*)(kvrow + 0);
  float4 k1 = *(const float4*)(kvrow + 4);
  float4 k2 = *(const float4*)(kvrow + 8);
  float4 k3 = *(const float4*)(kvrow + 12);

  for (int kk = 0; kk < 18; ++kk) {       // 576 / 32
    __syncthreads();                       // previous tile fully consumed
    int4 wa0 = { (int)pk2(q0.x, q0.y), (int)pk2(q0.z, q0.w), (int)pk2(q1.x, q1.y), (int)pk2(q1.z, q1.w) };
    int4 wa1 = { (int)pk2(q2.x, q2.y), (int)pk2(q2.z, q2.w), (int)pk2(q3.x, q3.y), (int)pk2(q3.z, q3.w) };
    int4 wb0 = { (int)pk2(k0.x, k0.y), (int)pk2(k0.z, k0.w), (int)pk2(k1.x, k1.y), (int)pk2(k1.z, k1.w) };
    int4 wb1 = { (int)pk2(k2.x, k2.y), (int)pk2(k2.z, k2.w), (int)pk2(k3.x, k3.y), (int)pk2(k3.z, k3.w) };
    *(int4*)aw = wa0; *(int4*)(aw + 8) = wa1;
    *(int4*)bw = wb0; *(int4*)(bw + 8) = wb1;
    __syncthreads();

    if (kk < 17) {                         // prefetch next tile; completes during MFMA below
      qrow += 32; kvrow += 32;
      q0 = *(const float4*)(qrow + 0);
      q1 = *(const float4*)(qrow + 4);
      q2 = *(const float4*)(qrow + 8);
      q3 = *(const float4*)(qrow + 12);
      k0 = *(const float4*)(kvrow + 0);
      k1 = *(const float4*)(kvrow + 4);
      k2 = *(const float4*)(kvrow + 8);
      k3 = *(const float4*)(kvrow + 12);
    }

    bf16x8 af[4], bfr[4];
#pragma unroll
    for (int i = 0; i < 4; ++i) af[i]  = *(const bf16x8*)&As[(wm * 64 + i * 16 + m16) * LSTR + quad * 8];
#pragma unroll
    for (int j = 0; j < 4; ++j) bfr[j] = *(const bf16x8*)&Bs[(wn * 64 + j * 16 + m16) * LSTR + quad * 8];
#pragma unroll
    for (int i = 0; i < 4; ++i)
#pragma unroll
      for (int j = 0; j < 4; ++j)
        acc[i][j] = __builtin_amdgcn_mfma_f32_16x16x32_bf16(af[i], bfr[j], acc[i][j], 0, 0, 0);
  }

  // epilogue: C/D layout col = lane&15 (key), row = quad*4 + reg (head)
#pragma unroll
  for (int i = 0; i < 4; ++i)
#pragma unroll
    for (int j = 0; j < 4; ++j)
#pragma unroll
      for (int r = 0; r < 4; ++r) {
        int h = wm * 64 + i * 16 + quad * 4 + r;
        int n = nt * 128 + wn * 64 + j * 16 + m16;
        S[((size_t)b * NH + h) * NTOP + n] = acc[i][j][r] * SCALE;
      }
}

// ---------------- Kernel 2: rowwise softmax over 2048, write normalized bf16 P ----------------
__global__ __launch_bounds__(256) void softmax_k(const float* __restrict__ S, unsigned short* __restrict__ P) {
  int row = blockIdx.x;                    // b*128 + h
  const float* s = S + (size_t)row * NTOP;
  unsigned short* p = P + (size_t)row * NTOP;
  int t = threadIdx.x;
  int lane = t & 63, wv = t >> 6;
  __shared__ float red[4];

  float4 v0 = *(const float4*)(s + t * 4);
  float4 v1 = *(const float4*)(s + 1024 + t * 4);

  float lm = fmaxf(fmaxf(fmaxf(v0.x, v0.y), fmaxf(v0.z, v0.w)),
                   fmaxf(fmaxf(v1.x, v1.y), fmaxf(v1.z, v1.w)));
  for (int off = 32; off > 0; off >>= 1) lm = fmaxf(lm, __shfl_down(lm, off));
  if (lane == 0) red[wv] = lm;
  __syncthreads();
  float m = fmaxf(fmaxf(red[0], red[1]), fmaxf(red[2], red[3]));

  float e0 = expf(v0.x - m), e1 = expf(v0.y - m), e2 = expf(v0.z - m), e3 = expf(v0.w - m);
  float e4 = expf(v1.x - m), e5 = expf(v1.y - m), e6 = expf(v1.z - m), e7 = expf(v1.w - m);
  float ls = ((e0 + e1) + (e2 + e3)) + ((e4 + e5) + (e6 + e7));
  for (int off = 32; off > 0; off >>= 1) ls += __shfl_down(ls, off);
  __syncthreads();                          // everyone done reading red from max phase
  if (lane == 0) red[wv] = ls;
  __syncthreads();
  float inv = 1.0f / (((red[0] + red[1]) + (red[2] + red[3])));

  uint2 o0 = { pk2(e0 * inv, e1 * inv), pk2(e2 * inv, e3 * inv) };
  uint2 o1 = { pk2(e4 * inv, e5 * inv), pk2(e6 * inv, e7 * inv) };
  *(uint2*)(p + t * 4) = o0;
  *(uint2*)(p + 1024 + t * 4) = o1;
}

// ---------------- Kernel 3: Out[b][h][d] += P[b][h][k] * KV[b][idx[k]][d]  (d<512), K-split x4 ----------------
// Baseline structure + register prefetch of next P/V chunks and next idx during MFMA.
__global__ __launch_bounds__(256) void gemm_pv(const unsigned short* __restrict__ P, const float* __restrict__ KV,
                                               const int* __restrict__ Idx, float* __restrict__ Out) {
  __shared__ short As[128 * LSTR];          // P tile [128h][32k]
  __shared__ short Bt[128 * LSTR];          // V^T tile [128d][32k]
  int wg = blockIdx.x;
  int b = wg >> 4, nt = (wg >> 2) & 3, ks = wg & 3;   // d-tile of 128, K-split of 512
  int t = threadIdx.x;

  int arow = t >> 1, ahalf = t & 1;
  const unsigned short* prow = P + ((size_t)b * NH + arow) * NTOP + ks * 512 + ahalf * 16;
  short* aw = &As[arow * LSTR + ahalf * 16];

  // B staging: lane covers key = t&31, d-chunk = (t>>5)*16
  int brow = t & 31;
  int bcol = (t >> 5) * 16;
  const int* idxp = Idx + b * NTOP + ks * 512 + brow;
  short* bw = &Bt[bcol * LSTR + brow];

  int lane = t & 63, wv = t >> 6;
  int wm = wv & 1, wn = wv >> 1;
  int m16 = lane & 15, quad = lane >> 4;

  f32x4 acc[4][4] = {};

  // preload iteration 0
  uint4 p0 = *(const uint4*)(prow);
  uint4 p1 = *(const uint4*)(prow + 8);
  int idx = idxp[0];
  const float* vrow = KV + ((size_t)b * NKV + (size_t)idx) * DQK + nt * 128 + bcol;
  float4 v0 = *(const float4*)(vrow + 0);
  float4 v1 = *(const float4*)(vrow + 4);
  float4 v2 = *(const float4*)(vrow + 8);
  float4 v3 = *(const float4*)(vrow + 12);

  for (int kk = 0; kk < 16; ++kk) {        // 512 / 32
    __syncthreads();
    *(uint4*)aw = p0; *(uint4*)(aw + 8) = p1;
    // transposed scatter: Bt[d_local][key]
    bw[0 * LSTR]  = f2bf(v0.x); bw[1 * LSTR]  = f2bf(v0.y); bw[2 * LSTR]  = f2bf(v0.z); bw[3 * LSTR]  = f2bf(v0.w);
    bw[4 * LSTR]  = f2bf(v1.x); bw[5 * LSTR]  = f2bf(v1.y); bw[6 * LSTR]  = f2bf(v1.z); bw[7 * LSTR]  = f2bf(v1.w);
    bw[8 * LSTR]  = f2bf(v2.x); bw[9 * LSTR]  = f2bf(v2.y); bw[10 * LSTR] = f2bf(v2.z); bw[11 * LSTR] = f2bf(v2.w);
    bw[12 * LSTR] = f2bf(v3.x); bw[13 * LSTR] = f2bf(v3.y); bw[14 * LSTR] = f2bf(v3.z); bw[15 * LSTR] = f2bf(v3.w);
    __syncthreads();

    if (kk < 15) {                          // prefetch next tile; completes during MFMA below
      prow += 32;
      p0 = *(const uint4*)(prow);
      p1 = *(const uint4*)(prow + 8);
      int nidx = idxp[(kk + 1) * 32];       // L1/L2-hot after first touches
      const float* nv = KV + ((size_t)b * NKV + (size_t)nidx) * DQK + nt * 128 + bcol;
      v0 = *(const float4*)(nv + 0);
      v1 = *(const float4*)(nv + 4);
      v2 = *(const float4*)(nv + 8);
      v3 = *(const float4*)(nv + 12);
    }

    bf16x8 af[4], bfr[4];
#pragma unroll
    for (int i = 0; i < 4; ++i) af[i]  = *(const bf16x8*)&As[(wm * 64 + i * 16 + m16) * LSTR + quad * 8];
#pragma unroll
    for (int j = 0; j < 4; ++j) bfr[j] = *(const bf16x8*)&Bt[(wn * 64 + j * 16 + m16) * LSTR + quad * 8];
#pragma unroll
    for (int i = 0; i < 4; ++i)
#pragma unroll
      for (int j = 0; j < 4; ++j)
        acc[i][j] = __builtin_amdgcn_mfma_f32_16x16x32_bf16(af[i], bfr[j], acc[i][j], 0, 0, 0);
  }

#pragma unroll
  for (int i = 0; i < 4; ++i)
#pragma unroll
    for (int j = 0; j < 4; ++j)
#pragma unroll
      for (int r = 0; r < 4; ++r) {
        int h = wm * 64 + i * 16 + quad * 4 + r;
        int d = nt * 128 + wn * 64 + j * 16 + m16;
        atomicAdd(&Out[((size_t)b * NH + h) * DV + d], acc[i][j][r]);
      }
}

extern "C" void kernel_launch(void* const* d_in, const int* in_sizes, int n_in,
                              void* d_out, int out_size, void* d_ws, size_t ws_size,
                              hipStream_t stream) {
  (void)in_sizes; (void)n_in; (void)ws_size;
  const float* Q  = (const float*)d_in[0];
  const float* KV = (const float*)d_in[1];
  const int*  Idx = (const int*)d_in[2];

  float* S = (float*)d_ws;                                             // 32*128*2048*4 = 33.55 MB
  unsigned short* P = (unsigned short*)((char*)d_ws + (size_t)NB * NH * NTOP * 4);  // 16.78 MB
  float* Out = (float*)d_out;

  (void)hipMemsetAsync(d_out, 0, (size_t)out_size * sizeof(float), stream);
  gemm_qk<<<dim3(NB * 16), dim3(256), 0, stream>>>(Q, KV, Idx, S);
  softmax_k<<<dim3(NB * NH), dim3(256), 0, stream>>>(S, P);
  gemm_pv<<<dim3(NB * 16), dim3(256), 0, stream>>>(P, KV, Idx, Out);
}